// Round 4
// baseline (9237.582 us; speedup 1.0000x reference)
//
#include <hip/hip_runtime.h>
#include <hip/hip_bf16.h>
#include <stdint.h>

#define BB 64
#define TT 32
#define HID 512
#define XD  512
#define NV  10000

#define GRID  512
#define NCELL 128
#define VB    64
#define NLOG  157        // ceil(10000/64)
#define PFB   192        // first prefetch block
#define NPF   (GRID - PFB)   // 320 prefetch blocks
// W_lin[t] = HID*NV floats = 1,280,000 float4 -> 4000 float4 per prefetch block

typedef __bf16 bf16x8 __attribute__((ext_vector_type(8)));
typedef float  f32x4  __attribute__((ext_vector_type(4)));

__device__ inline void split2(float w, __bf16& hi, __bf16& lo) {
  hi = (__bf16)w;
  lo = (__bf16)(w - (float)hi);
}

__device__ inline unsigned long long shflxor64(unsigned long long v, int m) {
  unsigned lo = (unsigned)(v & 0xFFFFFFFFull);
  unsigned hi = (unsigned)(v >> 32);
  lo = __shfl_xor(lo, m);
  hi = __shfl_xor(hi, m);
  return ((unsigned long long)hi << 32) | lo;
}

// monotonic packing of (logit, vocab index); larger u64 = larger logit,
// ties broken toward SMALLER index (matches jnp.argmax first-occurrence).
__device__ inline unsigned long long packkey(float f, int v) {
  unsigned ub = __float_as_uint(f);
  unsigned key = (ub & 0x80000000u) ? ~ub : (ub | 0x80000000u);
  return ((unsigned long long)key << 32) | (unsigned)(0xFFFFFFFFu - (unsigned)v);
}

__device__ inline void spin_until(int* ctr, int target) {
  if (threadIdx.x == 0) {
    while (__hip_atomic_load(ctr, __ATOMIC_ACQUIRE, __HIP_MEMORY_SCOPE_AGENT) < target)
      __builtin_amdgcn_s_sleep(2);
  }
  __syncthreads();
}

__device__ inline void mark_done(int* ctr) {
  __threadfence();            // every thread: stores visible at device scope
  __syncthreads();            // all threads' fences complete before the add
  if (threadIdx.x == 0)
    __hip_atomic_fetch_add(ctr, 1, __ATOMIC_RELEASE, __HIP_MEMORY_SCOPE_AGENT);
}

struct Params {
  const float *x, *emb;
  const float *Whi, *Whf, *Who, *Whz;
  const float *Wxi, *Wxf, *Wxo, *Wxz;
  const float *bi, *bfg, *bo, *bz;
  const float *W_lin, *b_lin;
  float* out;
  __bf16 *h_hi, *h_lo;
  float* c_ws;
  unsigned long long* gmax;   // [TT][BB] per-step, zeroed in k_init
  float* gsum;                // [TT][BB]
  int *cd, *ld;               // cell_done[TT], logits_done[TT]
};

struct SMCell { __bf16 Bh[16][136]; __bf16 Bl[16][136]; float pre[64][17]; };
struct SMLog  { __bf16 Bh[VB][136]; __bf16 Bl[VB][136]; };
union SMU { SMCell c; SMLog l; };

__global__ __launch_bounds__(256) void k_init(
    const float* __restrict__ h0, const float* __restrict__ c0,
    __bf16* __restrict__ h_hi, __bf16* __restrict__ h_lo,
    float* __restrict__ c_ws,
    unsigned long long* __restrict__ gmax, float* __restrict__ gsum,
    int* __restrict__ ctrs) {
  int i = blockIdx.x * 256 + threadIdx.x;   // grid = 128 blocks = BB*HID threads
  float h = h0[i];
  __bf16 hi, lo; split2(h, hi, lo);
  h_hi[i] = hi; h_lo[i] = lo;
  c_ws[i] = c0[i];
  if (blockIdx.x == 0 && threadIdx.x < 64) ctrs[threadIdx.x] = 0;   // cd[32]+ld[32]
  if (blockIdx.x >= 1 && blockIdx.x <= 8) {
    int j = (blockIdx.x - 1) * 256 + threadIdx.x;                   // 0..2047
    gmax[j] = 0ULL;
    gsum[j] = 0.f;
  }
}

__device__ inline void pf_stream(const float4* __restrict__ base,
                                 int pid, int tid, int nf4) {
  float s = 0.f;
  for (int i = tid; i < nf4; i += 256) {
    float4 v = base[(size_t)pid * nf4 + i];
    s += v.x + v.y + v.z + v.w;
  }
  asm volatile("" :: "v"(s));   // keep prefetch loads live (rule #17)
}

__global__ __launch_bounds__(256, 2) void k_main(Params p) {
  __shared__ SMU sm;
  const int bid = blockIdx.x, tid = threadIdx.x;
  const int lane = tid & 63, wid = tid >> 6;

  for (int t = 0; t < TT; t++) {
    const int pc = t & 1, po = pc ^ 1;

    // ---------------- prefetch pool (blocks 192..511) ----------------
    if (bid >= PFB) {
      int pid = bid - PFB;
      if (t <= 30) {
        if (t >= 1) spin_until(&p.cd[t - 1], NCELL);  // ~1-step lookahead throttle
        // W_lin[t] feeds logits(t+1) (lidx = t)
        pf_stream((const float4*)(p.W_lin + (size_t)t * HID * NV), pid, tid, 4000);
        if (pid == 0) {   // b_lin[t] (10000 floats = 2500 float4)
          float s = 0.f;
          const float4* bp = (const float4*)(p.b_lin + (size_t)t * NV);
          for (int i = tid; i < 2500; i += 256) {
            float4 v = bp[i]; s += v.x + v.y + v.z + v.w;
          }
          asm volatile("" :: "v"(s));
        }
      }
      if (t == 0)   // warm embedding table (20.5 MB) into LLC once
        pf_stream((const float4*)p.emb, pid, tid, 4000);
      continue;     // prefetchers do nothing else this iteration
    }

    // ---------------- cell (0..127) / normalize y[t-1] (128..191) ----------
    if (bid < NCELL) {
      if (t > 0) spin_until(&p.ld[t - 1], NLOG);

      const int n0 = bid * 4;
      const int row = wid * 16 + (lane & 15);
      const __bf16* hr  = p.h_hi + (size_t)pc * BB * HID;
      const __bf16* hrl = p.h_lo + (size_t)pc * BB * HID;
      __bf16* hw  = p.h_hi + (size_t)po * BB * HID;
      __bf16* hwl = p.h_lo + (size_t)po * BB * HID;

      const float* xrow;
      if (t == 0) {
        xrow = p.x + (size_t)row * TT * XD;          // x[row][0][:]
      } else {
        unsigned long long mk = p.gmax[(size_t)(t - 1) * BB + row];
        int tok = (int)(0xFFFFFFFFu - (unsigned)(mk & 0xFFFFFFFFull));
        xrow = p.emb + (size_t)tok * XD;
      }

      const float* WH[4] = {p.Whi, p.Whf, p.Who, p.Whz};
      const float* WX[4] = {p.Wxi, p.Wxf, p.Wxo, p.Wxz};

      f32x4 accA = {0.f, 0.f, 0.f, 0.f};
      f32x4 accB = {0.f, 0.f, 0.f, 0.f};

      for (int k0 = 0; k0 < 2 * HID; k0 += 128) {
        bool isH = (k0 < HID);
        __syncthreads();
        #pragma unroll
        for (int i2 = 0; i2 < 2; i2++) {
          int e = tid + i2 * 256;           // e = k*4 + g
          int k = e >> 2, g = e & 3;
          const float* src = isH ? (WH[g] + (size_t)(k0 + k) * HID + n0)
                                 : (WX[g] + (size_t)(k0 + k - HID) * HID + n0);
          float4 w = *(const float4*)src;
          #pragma unroll
          for (int j = 0; j < 4; j++) {
            float wv = ((const float*)&w)[j];
            __bf16 hi, lo; split2(wv, hi, lo);
            sm.c.Bh[g * 4 + j][k] = hi;
            sm.c.Bl[g * 4 + j][k] = lo;
          }
        }
        __syncthreads();

        #pragma unroll
        for (int ks = 0; ks < 4; ks++) {
          int kk = k0 + ks * 32 + (lane >> 4) * 8;
          bf16x8 ah, al;
          if (isH) {
            ah = *(const bf16x8*)(hr  + (size_t)row * HID + kk);
            al = *(const bf16x8*)(hrl + (size_t)row * HID + kk);
          } else {
            const float* xp = xrow + (kk - HID);
            float4 w0 = *(const float4*)(xp);
            float4 w1 = *(const float4*)(xp + 4);
            #pragma unroll
            for (int j = 0; j < 4; j++) {
              __bf16 hi, lo;
              split2(((const float*)&w0)[j], hi, lo); ah[j] = hi; al[j] = lo;
              split2(((const float*)&w1)[j], hi, lo); ah[4 + j] = hi; al[4 + j] = lo;
            }
          }
          int kl = ks * 32 + (lane >> 4) * 8;
          bf16x8 bh = *(const bf16x8*)&sm.c.Bh[lane & 15][kl];
          bf16x8 bl = *(const bf16x8*)&sm.c.Bl[lane & 15][kl];
          accA = __builtin_amdgcn_mfma_f32_16x16x32_bf16(ah, bh, accA, 0, 0, 0);
          accB = __builtin_amdgcn_mfma_f32_16x16x32_bf16(ah, bl, accB, 0, 0, 0);
          accB = __builtin_amdgcn_mfma_f32_16x16x32_bf16(al, bh, accB, 0, 0, 0);
          accA = __builtin_amdgcn_mfma_f32_16x16x32_bf16(al, bl, accA, 0, 0, 0);
        }
      }

      __syncthreads();
      #pragma unroll
      for (int j = 0; j < 4; j++)
        sm.c.pre[wid * 16 + (lane >> 4) * 4 + j][lane & 15] = accA[j] + accB[j];
      __syncthreads();

      {
        int rloc = tid >> 2, q = tid & 3;
        int n = n0 + q;
        float pi = sm.c.pre[rloc][q]      + p.bi[n];
        float pf = sm.c.pre[rloc][4 + q]  + p.bfg[n];
        float pq = sm.c.pre[rloc][8 + q]  + p.bo[n];
        float pz = sm.c.pre[rloc][12 + q] + p.bz[n];
        float ig = 1.f / (1.f + expf(-pi));
        float fg = 1.f / (1.f + expf(-pf));
        float og = 1.f / (1.f + expf(-pq));
        float zg = tanhf(pz);
        float cp = p.c_ws[rloc * HID + n];
        float cn = ig * zg + fg * cp;
        p.c_ws[rloc * HID + n] = cn;
        p.out[(size_t)BB * TT * NV + (size_t)rloc * TT * HID + (size_t)t * HID + n] = cn;
        float hn = og * tanhf(cn);
        __bf16 hh, hl; split2(hn, hh, hl);
        hw [rloc * HID + n] = hh;
        hwl[rloc * HID + n] = hl;
      }
      mark_done(&p.cd[t]);
    } else {
      // ---------------- normalize y[t-1] (blocks 128..191) ----------------
      if (t > 0) {
        spin_until(&p.ld[t - 1], NLOG);
        int r = bid - NCELL;
        float inv = 1.0f / p.gsum[(size_t)(t - 1) * BB + r];
        float4* y4 = (float4*)(p.out + (size_t)r * TT * NV + (size_t)(t - 1) * NV);
        for (int i = tid; i < NV / 4; i += 256) {
          float4 v = y4[i];
          v.x *= inv; v.y *= inv; v.z *= inv; v.w *= inv;
          y4[i] = v;
        }
      }
    }

    // ---------------- logits (blocks 0..156) ----------------
    if (bid < NLOG) {
      spin_until(&p.cd[t], NCELL);

      const int lidx = (t == 0) ? 0 : t - 1;
      const float* W = p.W_lin + (size_t)lidx * HID * NV;
      const __bf16* hhi = p.h_hi + (size_t)po * BB * HID;
      const __bf16* hlo = p.h_lo + (size_t)po * BB * HID;
      const int v0 = bid * VB;

      f32x4 acc[4][2] = {};

      for (int k0 = 0; k0 < HID; k0 += 128) {
        __syncthreads();
        #pragma unroll
        for (int i2 = 0; i2 < 8; i2++) {
          int e = tid + i2 * 256;           // e = k*16 + ppos
          int k = e >> 4, ppos = e & 15;
          // reads past v=9999 stay inside W_lin (lidx<=30), masked later
          float4 w = *(const float4*)(W + (size_t)(k0 + k) * NV + v0 + ppos * 4);
          #pragma unroll
          for (int j = 0; j < 4; j++) {
            float wv = ((const float*)&w)[j];
            __bf16 hi, lo; split2(wv, hi, lo);
            sm.l.Bh[ppos * 4 + j][k] = hi;
            sm.l.Bl[ppos * 4 + j][k] = lo;
          }
        }
        __syncthreads();

        int row = wid * 16 + (lane & 15);
        #pragma unroll
        for (int ks = 0; ks < 4; ks++) {
          int kk = k0 + ks * 32 + (lane >> 4) * 8;
          bf16x8 ah = *(const bf16x8*)(hhi + (size_t)row * HID + kk);
          bf16x8 al = *(const bf16x8*)(hlo + (size_t)row * HID + kk);
          int kl = ks * 32 + (lane >> 4) * 8;
          #pragma unroll
          for (int vt = 0; vt < 4; vt++) {
            bf16x8 bh = *(const bf16x8*)&sm.l.Bh[vt * 16 + (lane & 15)][kl];
            bf16x8 bl = *(const bf16x8*)&sm.l.Bl[vt * 16 + (lane & 15)][kl];
            acc[vt][0] = __builtin_amdgcn_mfma_f32_16x16x32_bf16(ah, bh, acc[vt][0], 0, 0, 0);
            acc[vt][1] = __builtin_amdgcn_mfma_f32_16x16x32_bf16(ah, bl, acc[vt][1], 0, 0, 0);
            acc[vt][1] = __builtin_amdgcn_mfma_f32_16x16x32_bf16(al, bh, acc[vt][1], 0, 0, 0);
            acc[vt][0] = __builtin_amdgcn_mfma_f32_16x16x32_bf16(al, bl, acc[vt][0], 0, 0, 0);
          }
        }
      }

      const float* brow = p.b_lin + (size_t)lidx * NV;
      float rsum[4] = {0.f, 0.f, 0.f, 0.f};
      unsigned long long rmax[4] = {0ULL, 0ULL, 0ULL, 0ULL};

      #pragma unroll
      for (int vt = 0; vt < 4; vt++) {
        int v = v0 + vt * 16 + (lane & 15);
        if (v < NV) {
          float bb = brow[v];
          #pragma unroll
          for (int j = 0; j < 4; j++) {
            int r = wid * 16 + (lane >> 4) * 4 + j;
            float logit = acc[vt][0][j] + acc[vt][1][j] + bb;
            float e = expf(logit);          // no max-subtract: |logit| small
            p.out[(size_t)r * TT * NV + (size_t)t * NV + v] = e;
            rsum[j] += e;
            unsigned long long pk = packkey(logit, v);
            if (pk > rmax[j]) rmax[j] = pk;
          }
        }
      }

      #pragma unroll
      for (int off = 1; off < 16; off <<= 1) {
        #pragma unroll
        for (int j = 0; j < 4; j++) {
          rsum[j] += __shfl_xor(rsum[j], off);
          unsigned long long o = shflxor64(rmax[j], off);
          if (o > rmax[j]) rmax[j] = o;
        }
      }
      if ((lane & 15) == 0) {
        #pragma unroll
        for (int j = 0; j < 4; j++) {
          int r = wid * 16 + (lane >> 4) * 4 + j;
          atomicAdd(&p.gsum[(size_t)t * BB + r], rsum[j]);
          atomicMax(&p.gmax[(size_t)t * BB + r], rmax[j]);
        }
      }
      mark_done(&p.ld[t]);
    }
  }

  // ---------------- final normalize of y[31] (blocks 128..191) ----------------
  if (bid >= NCELL && bid < PFB) {
    spin_until(&p.ld[TT - 1], NLOG);
    int r = bid - NCELL;
    float inv = 1.0f / p.gsum[(size_t)(TT - 1) * BB + r];
    float4* y4 = (float4*)(p.out + (size_t)r * TT * NV + (size_t)(TT - 1) * NV);
    for (int i = tid; i < NV / 4; i += 256) {
      float4 v = y4[i];
      v.x *= inv; v.y *= inv; v.z *= inv; v.w *= inv;
      y4[i] = v;
    }
  }
}

extern "C" void kernel_launch(void* const* d_in, const int* in_sizes, int n_in,
                              void* d_out, int out_size, void* d_ws, size_t ws_size,
                              hipStream_t stream) {
  const float* x     = (const float*)d_in[0];
  const float* h0    = (const float*)d_in[1];
  const float* c0    = (const float*)d_in[2];
  const float* W_hi  = (const float*)d_in[3];
  const float* W_xi  = (const float*)d_in[4];
  const float* b_i   = (const float*)d_in[5];
  const float* W_hf  = (const float*)d_in[6];
  const float* W_xf  = (const float*)d_in[7];
  const float* b_f   = (const float*)d_in[8];
  const float* W_ho  = (const float*)d_in[9];
  const float* W_xo  = (const float*)d_in[10];
  const float* b_o   = (const float*)d_in[11];
  const float* W_hz  = (const float*)d_in[12];
  const float* W_xz  = (const float*)d_in[13];
  const float* b_z   = (const float*)d_in[14];
  const float* W_lin = (const float*)d_in[15];
  const float* b_lin = (const float*)d_in[16];
  const float* emb   = (const float*)d_in[17];

  float* out = (float*)d_out;
  char* ws = (char*)d_ws;
  __bf16* h_hi = (__bf16*)ws;                                    // [2][64][512]
  __bf16* h_lo = (__bf16*)(ws + 131072);                         // [2][64][512]
  float*  c_ws = (float*)(ws + 262144);                          // [64][512]
  unsigned long long* gmax = (unsigned long long*)(ws + 393216); // [32][64]
  float*  gsum = (float*)(ws + 409600);                          // [32][64]
  int*    ctrs = (int*)(ws + 417792);                            // cd[32] ld[32]

  k_init<<<128, 256, 0, stream>>>(h0, c0, h_hi, h_lo, c_ws, gmax, gsum, ctrs);

  Params P;
  P.x = x; P.emb = emb;
  P.Whi = W_hi; P.Whf = W_hf; P.Who = W_ho; P.Whz = W_hz;
  P.Wxi = W_xi; P.Wxf = W_xf; P.Wxo = W_xo; P.Wxz = W_xz;
  P.bi = b_i; P.bfg = b_f; P.bo = b_o; P.bz = b_z;
  P.W_lin = W_lin; P.b_lin = b_lin;
  P.out = out;
  P.h_hi = h_hi; P.h_lo = h_lo; P.c_ws = c_ws;
  P.gmax = gmax; P.gsum = gsum;
  P.cd = ctrs; P.ld = ctrs + 32;

  k_main<<<GRID, 256, 0, stream>>>(P);
}

// Round 5
// 2515.369 us; speedup vs baseline: 3.6725x; 3.6725x over previous
//
#include <hip/hip_runtime.h>
#include <hip/hip_bf16.h>
#include <stdint.h>

#define BB 64
#define TT 32
#define HID 512
#define XD  512
#define NV  10000

#define GRID  512
#define NCELL 128
#define VB    64
#define NLOG  157        // ceil(10000/64)
#define PFB   192        // first prefetch block
#define NPF   (GRID - PFB)   // 320 prefetch blocks
// W_lin[t] = HID*NV floats = 1,280,000 float4 -> 4000 float4 per prefetch block

typedef __bf16 bf16x8 __attribute__((ext_vector_type(8)));
typedef float  f32x4  __attribute__((ext_vector_type(4)));

__device__ inline void split2(float w, __bf16& hi, __bf16& lo) {
  hi = (__bf16)w;
  lo = (__bf16)(w - (float)hi);
}

__device__ inline unsigned long long shflxor64(unsigned long long v, int m) {
  unsigned lo = (unsigned)(v & 0xFFFFFFFFull);
  unsigned hi = (unsigned)(v >> 32);
  lo = __shfl_xor(lo, m);
  hi = __shfl_xor(hi, m);
  return ((unsigned long long)hi << 32) | lo;
}

// monotonic packing of (logit, vocab index); larger u64 = larger logit,
// ties broken toward SMALLER index (matches jnp.argmax first-occurrence).
__device__ inline unsigned long long packkey(float f, int v) {
  unsigned ub = __float_as_uint(f);
  unsigned key = (ub & 0x80000000u) ? ~ub : (ub | 0x80000000u);
  return ((unsigned long long)key << 32) | (unsigned)(0xFFFFFFFFu - (unsigned)v);
}

// RELAXED poll (no per-iteration cache inv), ONE acquire load at the end.
__device__ inline void spin_until(int* ctr, int target) {
  if (threadIdx.x == 0) {
    while (__hip_atomic_load(ctr, __ATOMIC_RELAXED, __HIP_MEMORY_SCOPE_AGENT) < target)
      __builtin_amdgcn_s_sleep(2);
    (void)__hip_atomic_load(ctr, __ATOMIC_ACQUIRE, __HIP_MEMORY_SCOPE_AGENT); // 1 inv
  }
  __syncthreads();
}

// RELAXED poll only — for the prefetch throttle (read-only data, no fence needed).
__device__ inline void spin_relaxed(int* ctr, int target) {
  if (threadIdx.x == 0) {
    while (__hip_atomic_load(ctr, __ATOMIC_RELAXED, __HIP_MEMORY_SCOPE_AGENT) < target)
      __builtin_amdgcn_s_sleep(2);
  }
  __syncthreads();
}

// __syncthreads() drains all threads' stores to L2 (compiler emits vmcnt(0)
// before s_barrier); ONE release fetch_add (one L2 writeback) publishes them.
__device__ inline void mark_done(int* ctr) {
  __syncthreads();
  if (threadIdx.x == 0)
    __hip_atomic_fetch_add(ctr, 1, __ATOMIC_RELEASE, __HIP_MEMORY_SCOPE_AGENT);
}

struct Params {
  const float *x, *emb;
  const float *Whi, *Whf, *Who, *Whz;
  const float *Wxi, *Wxf, *Wxo, *Wxz;
  const float *bi, *bfg, *bo, *bz;
  const float *W_lin, *b_lin;
  float* out;
  __bf16 *h_hi, *h_lo;
  float* c_ws;
  unsigned long long* gmax;   // [TT][BB] per-step, zeroed in k_init
  float* gsum;                // [TT][BB]
  int *cd, *ld;               // cell_done[TT], logits_done[TT]
};

struct SMCell { __bf16 Bh[16][136]; __bf16 Bl[16][136]; float pre[64][17]; };
struct SMLog  { __bf16 Bh[VB][136]; __bf16 Bl[VB][136]; };
union SMU { SMCell c; SMLog l; };

__global__ __launch_bounds__(256) void k_init(
    const float* __restrict__ h0, const float* __restrict__ c0,
    __bf16* __restrict__ h_hi, __bf16* __restrict__ h_lo,
    float* __restrict__ c_ws,
    unsigned long long* __restrict__ gmax, float* __restrict__ gsum,
    int* __restrict__ ctrs) {
  int i = blockIdx.x * 256 + threadIdx.x;   // grid = 128 blocks = BB*HID threads
  float h = h0[i];
  __bf16 hi, lo; split2(h, hi, lo);
  h_hi[i] = hi; h_lo[i] = lo;
  c_ws[i] = c0[i];
  if (blockIdx.x == 0 && threadIdx.x < 64) ctrs[threadIdx.x] = 0;   // cd[32]+ld[32]
  if (blockIdx.x >= 1 && blockIdx.x <= 8) {
    int j = (blockIdx.x - 1) * 256 + threadIdx.x;                   // 0..2047
    gmax[j] = 0ULL;
    gsum[j] = 0.f;
  }
}

__device__ inline void pf_stream(const float4* __restrict__ base,
                                 int pid, int tid, int nf4) {
  float s = 0.f;
  for (int i = tid; i < nf4; i += 256) {
    float4 v = base[(size_t)pid * nf4 + i];
    s += v.x + v.y + v.z + v.w;
  }
  asm volatile("" :: "v"(s));   // keep prefetch loads live (rule #17)
}

__global__ __launch_bounds__(256, 2) void k_main(Params p) {
  __shared__ SMU sm;
  const int bid = blockIdx.x, tid = threadIdx.x;
  const int lane = tid & 63, wid = tid >> 6;

  for (int t = 0; t < TT; t++) {
    const int pc = t & 1, po = pc ^ 1;

    // ---------------- prefetch pool (blocks 192..511) ----------------
    if (bid >= PFB) {
      int pid = bid - PFB;
      if (t <= 30) {
        if (t >= 1) spin_relaxed(&p.cd[t - 1], NCELL);  // ~1-step lookahead throttle
        // W_lin[t] feeds logits(t+1) (lidx = t)
        pf_stream((const float4*)(p.W_lin + (size_t)t * HID * NV), pid, tid, 4000);
        if (pid == 0) {   // b_lin[t] (10000 floats = 2500 float4)
          float s = 0.f;
          const float4* bp = (const float4*)(p.b_lin + (size_t)t * NV);
          for (int i = tid; i < 2500; i += 256) {
            float4 v = bp[i]; s += v.x + v.y + v.z + v.w;
          }
          asm volatile("" :: "v"(s));
        }
      }
      if (t == 0)   // warm embedding table (20.5 MB) into LLC once
        pf_stream((const float4*)p.emb, pid, tid, 4000);
      continue;     // prefetchers do nothing else this iteration
    }

    // ---------------- cell (0..127) / normalize y[t-1] (128..191) ----------
    if (bid < NCELL) {
      if (t > 0) spin_until(&p.ld[t - 1], NLOG);

      const int n0 = bid * 4;
      const int row = wid * 16 + (lane & 15);
      const __bf16* hr  = p.h_hi + (size_t)pc * BB * HID;
      const __bf16* hrl = p.h_lo + (size_t)pc * BB * HID;
      __bf16* hw  = p.h_hi + (size_t)po * BB * HID;
      __bf16* hwl = p.h_lo + (size_t)po * BB * HID;

      const float* xrow;
      if (t == 0) {
        xrow = p.x + (size_t)row * TT * XD;          // x[row][0][:]
      } else {
        unsigned long long mk = p.gmax[(size_t)(t - 1) * BB + row];
        int tok = (int)(0xFFFFFFFFu - (unsigned)(mk & 0xFFFFFFFFull));
        xrow = p.emb + (size_t)tok * XD;
      }

      const float* WH[4] = {p.Whi, p.Whf, p.Who, p.Whz};
      const float* WX[4] = {p.Wxi, p.Wxf, p.Wxo, p.Wxz};

      f32x4 accA = {0.f, 0.f, 0.f, 0.f};
      f32x4 accB = {0.f, 0.f, 0.f, 0.f};

      for (int k0 = 0; k0 < 2 * HID; k0 += 128) {
        bool isH = (k0 < HID);
        __syncthreads();
        #pragma unroll
        for (int i2 = 0; i2 < 2; i2++) {
          int e = tid + i2 * 256;           // e = k*4 + g
          int k = e >> 2, g = e & 3;
          const float* src = isH ? (WH[g] + (size_t)(k0 + k) * HID + n0)
                                 : (WX[g] + (size_t)(k0 + k - HID) * HID + n0);
          float4 w = *(const float4*)src;
          #pragma unroll
          for (int j = 0; j < 4; j++) {
            float wv = ((const float*)&w)[j];
            __bf16 hi, lo; split2(wv, hi, lo);
            sm.c.Bh[g * 4 + j][k] = hi;
            sm.c.Bl[g * 4 + j][k] = lo;
          }
        }
        __syncthreads();

        #pragma unroll
        for (int ks = 0; ks < 4; ks++) {
          int kk = k0 + ks * 32 + (lane >> 4) * 8;
          bf16x8 ah, al;
          if (isH) {
            ah = *(const bf16x8*)(hr  + (size_t)row * HID + kk);
            al = *(const bf16x8*)(hrl + (size_t)row * HID + kk);
          } else {
            const float* xp = xrow + (kk - HID);
            float4 w0 = *(const float4*)(xp);
            float4 w1 = *(const float4*)(xp + 4);
            #pragma unroll
            for (int j = 0; j < 4; j++) {
              __bf16 hi, lo;
              split2(((const float*)&w0)[j], hi, lo); ah[j] = hi; al[j] = lo;
              split2(((const float*)&w1)[j], hi, lo); ah[4 + j] = hi; al[4 + j] = lo;
            }
          }
          int kl = ks * 32 + (lane >> 4) * 8;
          bf16x8 bh = *(const bf16x8*)&sm.c.Bh[lane & 15][kl];
          bf16x8 bl = *(const bf16x8*)&sm.c.Bl[lane & 15][kl];
          accA = __builtin_amdgcn_mfma_f32_16x16x32_bf16(ah, bh, accA, 0, 0, 0);
          accB = __builtin_amdgcn_mfma_f32_16x16x32_bf16(ah, bl, accB, 0, 0, 0);
          accB = __builtin_amdgcn_mfma_f32_16x16x32_bf16(al, bh, accB, 0, 0, 0);
          accA = __builtin_amdgcn_mfma_f32_16x16x32_bf16(al, bl, accA, 0, 0, 0);
        }
      }

      __syncthreads();
      #pragma unroll
      for (int j = 0; j < 4; j++)
        sm.c.pre[wid * 16 + (lane >> 4) * 4 + j][lane & 15] = accA[j] + accB[j];
      __syncthreads();

      {
        int rloc = tid >> 2, q = tid & 3;
        int n = n0 + q;
        float pi = sm.c.pre[rloc][q]      + p.bi[n];
        float pf = sm.c.pre[rloc][4 + q]  + p.bfg[n];
        float pq = sm.c.pre[rloc][8 + q]  + p.bo[n];
        float pz = sm.c.pre[rloc][12 + q] + p.bz[n];
        float ig = 1.f / (1.f + expf(-pi));
        float fg = 1.f / (1.f + expf(-pf));
        float og = 1.f / (1.f + expf(-pq));
        float zg = tanhf(pz);
        float cp = p.c_ws[rloc * HID + n];
        float cn = ig * zg + fg * cp;
        p.c_ws[rloc * HID + n] = cn;
        p.out[(size_t)BB * TT * NV + (size_t)rloc * TT * HID + (size_t)t * HID + n] = cn;
        float hn = og * tanhf(cn);
        __bf16 hh, hl; split2(hn, hh, hl);
        hw [rloc * HID + n] = hh;
        hwl[rloc * HID + n] = hl;
      }
      mark_done(&p.cd[t]);
    } else {
      // ---------------- normalize y[t-1] (blocks 128..191) ----------------
      if (t > 0) {
        spin_until(&p.ld[t - 1], NLOG);
        int r = bid - NCELL;
        float inv = 1.0f / p.gsum[(size_t)(t - 1) * BB + r];
        float4* y4 = (float4*)(p.out + (size_t)r * TT * NV + (size_t)(t - 1) * NV);
        for (int i = tid; i < NV / 4; i += 256) {
          float4 v = y4[i];
          v.x *= inv; v.y *= inv; v.z *= inv; v.w *= inv;
          y4[i] = v;
        }
      }
    }

    // ---------------- logits (blocks 0..156) ----------------
    if (bid < NLOG) {
      spin_until(&p.cd[t], NCELL);

      const int lidx = (t == 0) ? 0 : t - 1;
      const float* W = p.W_lin + (size_t)lidx * HID * NV;
      const __bf16* hhi = p.h_hi + (size_t)po * BB * HID;
      const __bf16* hlo = p.h_lo + (size_t)po * BB * HID;
      const int v0 = bid * VB;

      f32x4 acc[4][2] = {};

      for (int k0 = 0; k0 < HID; k0 += 128) {
        __syncthreads();
        #pragma unroll
        for (int i2 = 0; i2 < 8; i2++) {
          int e = tid + i2 * 256;           // e = k*16 + ppos
          int k = e >> 4, ppos = e & 15;
          // reads past v=9999 stay inside W_lin (lidx<=30), masked later
          float4 w = *(const float4*)(W + (size_t)(k0 + k) * NV + v0 + ppos * 4);
          #pragma unroll
          for (int j = 0; j < 4; j++) {
            float wv = ((const float*)&w)[j];
            __bf16 hi, lo; split2(wv, hi, lo);
            sm.l.Bh[ppos * 4 + j][k] = hi;
            sm.l.Bl[ppos * 4 + j][k] = lo;
          }
        }
        __syncthreads();

        int row = wid * 16 + (lane & 15);
        #pragma unroll
        for (int ks = 0; ks < 4; ks++) {
          int kk = k0 + ks * 32 + (lane >> 4) * 8;
          bf16x8 ah = *(const bf16x8*)(hhi + (size_t)row * HID + kk);
          bf16x8 al = *(const bf16x8*)(hlo + (size_t)row * HID + kk);
          int kl = ks * 32 + (lane >> 4) * 8;
          #pragma unroll
          for (int vt = 0; vt < 4; vt++) {
            bf16x8 bh = *(const bf16x8*)&sm.l.Bh[vt * 16 + (lane & 15)][kl];
            bf16x8 bl = *(const bf16x8*)&sm.l.Bl[vt * 16 + (lane & 15)][kl];
            acc[vt][0] = __builtin_amdgcn_mfma_f32_16x16x32_bf16(ah, bh, acc[vt][0], 0, 0, 0);
            acc[vt][1] = __builtin_amdgcn_mfma_f32_16x16x32_bf16(ah, bl, acc[vt][1], 0, 0, 0);
            acc[vt][1] = __builtin_amdgcn_mfma_f32_16x16x32_bf16(al, bh, acc[vt][1], 0, 0, 0);
            acc[vt][0] = __builtin_amdgcn_mfma_f32_16x16x32_bf16(al, bl, acc[vt][0], 0, 0, 0);
          }
        }
      }

      const float* brow = p.b_lin + (size_t)lidx * NV;
      float rsum[4] = {0.f, 0.f, 0.f, 0.f};
      unsigned long long rmax[4] = {0ULL, 0ULL, 0ULL, 0ULL};

      #pragma unroll
      for (int vt = 0; vt < 4; vt++) {
        int v = v0 + vt * 16 + (lane & 15);
        if (v < NV) {
          float bb = brow[v];
          #pragma unroll
          for (int j = 0; j < 4; j++) {
            int r = wid * 16 + (lane >> 4) * 4 + j;
            float logit = acc[vt][0][j] + acc[vt][1][j] + bb;
            float e = expf(logit);          // no max-subtract: |logit| small
            p.out[(size_t)r * TT * NV + (size_t)t * NV + v] = e;
            rsum[j] += e;
            unsigned long long pk = packkey(logit, v);
            if (pk > rmax[j]) rmax[j] = pk;
          }
        }
      }

      #pragma unroll
      for (int off = 1; off < 16; off <<= 1) {
        #pragma unroll
        for (int j = 0; j < 4; j++) {
          rsum[j] += __shfl_xor(rsum[j], off);
          unsigned long long o = shflxor64(rmax[j], off);
          if (o > rmax[j]) rmax[j] = o;
        }
      }
      if ((lane & 15) == 0) {
        #pragma unroll
        for (int j = 0; j < 4; j++) {
          int r = wid * 16 + (lane >> 4) * 4 + j;
          atomicAdd(&p.gsum[(size_t)t * BB + r], rsum[j]);
          atomicMax(&p.gmax[(size_t)t * BB + r], rmax[j]);
        }
      }
      mark_done(&p.ld[t]);
    }
  }

  // ---------------- final normalize of y[31] (blocks 128..191) ----------------
  if (bid >= NCELL && bid < PFB) {
    spin_until(&p.ld[TT - 1], NLOG);
    int r = bid - NCELL;
    float inv = 1.0f / p.gsum[(size_t)(TT - 1) * BB + r];
    float4* y4 = (float4*)(p.out + (size_t)r * TT * NV + (size_t)(TT - 1) * NV);
    for (int i = tid; i < NV / 4; i += 256) {
      float4 v = y4[i];
      v.x *= inv; v.y *= inv; v.z *= inv; v.w *= inv;
      y4[i] = v;
    }
  }
}

extern "C" void kernel_launch(void* const* d_in, const int* in_sizes, int n_in,
                              void* d_out, int out_size, void* d_ws, size_t ws_size,
                              hipStream_t stream) {
  const float* x     = (const float*)d_in[0];
  const float* h0    = (const float*)d_in[1];
  const float* c0    = (const float*)d_in[2];
  const float* W_hi  = (const float*)d_in[3];
  const float* W_xi  = (const float*)d_in[4];
  const float* b_i   = (const float*)d_in[5];
  const float* W_hf  = (const float*)d_in[6];
  const float* W_xf  = (const float*)d_in[7];
  const float* b_f   = (const float*)d_in[8];
  const float* W_ho  = (const float*)d_in[9];
  const float* W_xo  = (const float*)d_in[10];
  const float* b_o   = (const float*)d_in[11];
  const float* W_hz  = (const float*)d_in[12];
  const float* W_xz  = (const float*)d_in[13];
  const float* b_z   = (const float*)d_in[14];
  const float* W_lin = (const float*)d_in[15];
  const float* b_lin = (const float*)d_in[16];
  const float* emb   = (const float*)d_in[17];

  float* out = (float*)d_out;
  char* ws = (char*)d_ws;
  __bf16* h_hi = (__bf16*)ws;                                    // [2][64][512]
  __bf16* h_lo = (__bf16*)(ws + 131072);                         // [2][64][512]
  float*  c_ws = (float*)(ws + 262144);                          // [64][512]
  unsigned long long* gmax = (unsigned long long*)(ws + 393216); // [32][64]
  float*  gsum = (float*)(ws + 409600);                          // [32][64]
  int*    ctrs = (int*)(ws + 417792);                            // cd[32] ld[32]

  k_init<<<128, 256, 0, stream>>>(h0, c0, h_hi, h_lo, c_ws, gmax, gsum, ctrs);

  Params P;
  P.x = x; P.emb = emb;
  P.Whi = W_hi; P.Whf = W_hf; P.Who = W_ho; P.Whz = W_hz;
  P.Wxi = W_xi; P.Wxf = W_xf; P.Wxo = W_xo; P.Wxz = W_xz;
  P.bi = b_i; P.bfg = b_f; P.bo = b_o; P.bz = b_z;
  P.W_lin = W_lin; P.b_lin = b_lin;
  P.out = out;
  P.h_hi = h_hi; P.h_lo = h_lo; P.c_ws = c_ws;
  P.gmax = gmax; P.gsum = gsum;
  P.cd = ctrs; P.ld = ctrs + 32;

  k_main<<<GRID, 256, 0, stream>>>(P);
}